// Round 2
// baseline (567.132 us; speedup 1.0000x reference)
//
#include <hip/hip_runtime.h>
#include <hip/hip_bf16.h>
#include <stdint.h>

#define T_LEN   16384
#define HID     1024
#define KDIM    1024
#define CHUNK   64
#define NCHUNK  256   // T_LEN / CHUNK

typedef __bf16 bf16x8 __attribute__((ext_vector_type(8)));
typedef float  f32x4  __attribute__((ext_vector_type(4)));

__device__ inline ushort f2bf(float f) {
  union { float f; uint32_t u; } v; v.f = f;
  uint32_t r = v.u + 0x7FFF + ((v.u >> 16) & 1);   // RNE
  return (ushort)(r >> 16);
}
__device__ inline float bf2f(ushort u) {
  union { uint32_t u; float f; } v; v.u = ((uint32_t)u) << 16;
  return v.f;
}

__device__ inline void gload16(const void* g, void* l) {
  __builtin_amdgcn_global_load_lds(
      (const __attribute__((address_space(1))) void*)g,
      (__attribute__((address_space(3))) void*)l, 16, 0, 0);
}

// ---------------- prep: lambda (complex), exp(gamma) ----------------
__global__ __launch_bounds__(256) void prep_kernel(
    const float* __restrict__ nu_log, const float* __restrict__ theta_log,
    const float* __restrict__ gamma_log,
    float* __restrict__ lam_re, float* __restrict__ lam_im, float* __restrict__ eg) {
  int h = blockIdx.x * 256 + threadIdx.x;
  if (h < HID) {
    float mag = expf(-expf(nu_log[h]));
    float th  = expf(theta_log[h]);
    lam_re[h] = mag * cosf(th);
    lam_im[h] = mag * sinf(th);
    eg[h]     = expf(gamma_log[h]);
  }
}

// ---------------- fp32 -> bf16, vectorized x4 ----------------
__global__ __launch_bounds__(256) void convX(
    const float* __restrict__ src, ushort* __restrict__ dst) {
  size_t i = ((size_t)blockIdx.x * 256 + threadIdx.x) * 4;
  float4 v = *(const float4*)(src + i);
  ushort4 o;
  o.x = f2bf(v.x); o.y = f2bf(v.y); o.z = f2bf(v.z); o.w = f2bf(v.w);
  *(ushort4*)(dst + i) = o;
}

// ---------------- all weight prep in one kernel (z selects job) ----------------
__global__ __launch_bounds__(256) void weight_prep(
    const float* __restrict__ Bre, const float* __restrict__ Bim,
    const float* __restrict__ Cre, const float* __restrict__ Cim,
    const float* __restrict__ D,   const float* __restrict__ eg,
    ushort* __restrict__ BreT, ushort* __restrict__ BimT,
    ushort* __restrict__ CreB, ushort* __restrict__ CimB,
    ushort* __restrict__ DT) {
  __shared__ float tile[32][33];
  int z = blockIdx.z;
  if (z == 2 || z == 3) {
    const float* src = (z == 2) ? Cre : Cim;
    ushort* dst = (z == 2) ? CreB : CimB;
    float s = (z == 2) ? 1.0f : -1.0f;
    size_t base = ((size_t)blockIdx.y * 32 + (threadIdx.x >> 3)) * 1024 +
                  blockIdx.x * 32 + (threadIdx.x & 7) * 4;
    float4 v = *(const float4*)(src + base);
    ushort4 o;
    o.x = f2bf(v.x * s); o.y = f2bf(v.y * s);
    o.z = f2bf(v.z * s); o.w = f2bf(v.w * s);
    *(ushort4*)(dst + base) = o;
    return;
  }
  const float* src = (z == 0) ? Bre : (z == 1) ? Bim : D;
  ushort* dst = (z == 0) ? BreT : (z == 1) ? BimT : DT;
  bool scaled = (z < 2);
  int bx = blockIdx.x * 32;   // n-block
  int by = blockIdx.y * 32;   // k-block
  int tx = threadIdx.x & 31, ty = threadIdx.x >> 5;
#pragma unroll
  for (int r = 0; r < 32; r += 8)
    tile[ty + r][tx] = src[(size_t)(by + ty + r) * 1024 + bx + tx];
  __syncthreads();
  float sc = scaled ? eg[by + tx] : 1.0f;
#pragma unroll
  for (int r = 0; r < 32; r += 8)
    dst[(size_t)(bx + ty + r) * 1024 + by + tx] = f2bf(tile[tx][ty + r] * sc);
}

// ================= 256x256 software-pipelined 8-phase MFMA GEMM =================
// 512 threads = 8 waves (2 M x 4 N). Per-wave output 128x64.
// Fragments prefetched ONE PHASE AHEAD (ds_read of quad p+1 overlaps MFMA of quad p);
// compiler emits progressive lgkmcnt waits. One raw s_barrier per phase.
// vmcnt(2) only at P3/P7 (phases with no ds_reads). Segments chain with no drain.

#define BAR()   __builtin_amdgcn_s_barrier()
#define SETP(x) __builtin_amdgcn_s_setprio(x)
#define VMW(N)  asm volatile("s_waitcnt vmcnt(" #N ")" ::: "memory")

#define STAGE_HALF(G, LDA, R0, K0, LT, HALF)                         \
  do {                                                               \
    _Pragma("unroll")                                                \
    for (int is_ = 0; is_ < 2; ++is_) {                              \
      int seg_ = w * 2 + is_;                                        \
      int gr_ = (R0) + (HALF) * 128 + seg_ * 8 + (l >> 3);           \
      int gc_ = (K0) + (((l & 7) ^ (l >> 3)) << 3);                  \
      gload16((G) + (size_t)gr_ * (LDA) + gc_,                       \
              (LT) + (HALF) * 8192 + seg_ * 512);                    \
    }                                                                \
  } while (0)

#define DS_A(DST, BUF, QM)                                           \
  do {                                                               \
    _Pragma("unroll")                                                \
    for (int m_ = 0; m_ < 4; ++m_) {                                 \
      int r_ = (wr * 128 + (QM) * 64 + m_ * 16 + lo) * 64;           \
      DST[m_][0] = *(const bf16x8*)((BUF) + r_ + c0us);              \
      DST[m_][1] = *(const bf16x8*)((BUF) + r_ + c1us);              \
    }                                                                \
  } while (0)

#define DS_B(DST, BUF, QN)                                           \
  do {                                                               \
    _Pragma("unroll")                                                \
    for (int n_ = 0; n_ < 2; ++n_) {                                 \
      int r_ = (wc * 64 + (QN) * 32 + n_ * 16 + lo) * 64;            \
      DST[n_][0] = *(const bf16x8*)((BUF) + r_ + c0us);              \
      DST[n_][1] = *(const bf16x8*)((BUF) + r_ + c1us);              \
    }                                                                \
  } while (0)

#define MFMA_Q(QM, QN, AR, BR)                                       \
  do {                                                               \
    SETP(1);                                                         \
    _Pragma("unroll")                                                \
    for (int m_ = 0; m_ < 4; ++m_)                                   \
      _Pragma("unroll")                                              \
      for (int n_ = 0; n_ < 2; ++n_) {                               \
        f32x4* ac_ = &acc[(QM) * 4 + m_][(QN) * 2 + n_];             \
        *ac_ = __builtin_amdgcn_mfma_f32_16x16x32_bf16(              \
            AR[m_][0], BR[n_][0], *ac_, 0, 0, 0);                    \
        *ac_ = __builtin_amdgcn_mfma_f32_16x16x32_bf16(              \
            AR[m_][1], BR[n_][1], *ac_, 0, 0, 0);                    \
      }                                                              \
    SETP(0);                                                         \
  } while (0)

// NSEG GEMM segments of K=1024 each, accumulated into acc, phase stream unbroken.
template<int NSEG>
__device__ __forceinline__ void gemm256_pipe(
    const ushort* const Aseg[], const int ldaseg[], const ushort* const Bseg[],
    ushort* lds, int row0, int col0, int w, int l,
    int wr, int wc, int lo, int c0us, int c1us, f32x4 (&acc)[8][4]) {
  ushort* A0 = lds;
  ushort* A1 = lds + 16384;
  ushort* B0 = lds + 32768;
  ushort* B1 = lds + 49152;
  bf16x8 a0[4][2], a1[4][2], b0[2][2], b1[2][2];

  {
    const ushort* A = Aseg[0]; const int lda = ldaseg[0];
    const ushort* B = Bseg[0];
    // prologue: T0.A -> A0, T0.B -> B0, T1.A -> A1  (12 loads)
    STAGE_HALF(A, lda, row0, 0, A0, 0);
    STAGE_HALF(A, lda, row0, 0, A0, 1);
    STAGE_HALF(B, 1024, col0, 0, B0, 0);
    STAGE_HALF(B, 1024, col0, 0, B0, 1);
    STAGE_HALF(A, lda, row0, 64, A1, 0);
    STAGE_HALF(A, lda, row0, 64, A1, 1);
    VMW(4);              // T0's 8 loads landed; T1.A (4) in flight
    BAR();
    DS_A(a0, A0, 0);     // T0 quad-0 fragments (complete under first MFMAs)
    DS_B(b0, B0, 0);
  }

#pragma unroll
  for (int s = 0; s < NSEG; ++s) {
    const ushort* A = Aseg[s]; const int lda = ldaseg[s];
    const ushort* B = Bseg[s];
    const bool hn = (s + 1 < NSEG);
    const ushort* An = hn ? Aseg[s + 1] : (const ushort*)0;
    const int ldan = hn ? ldaseg[s + 1] : 0;
    const ushort* Bn = hn ? Bseg[s + 1] : (const ushort*)0;
#pragma unroll 1
    for (int i = 0; i < 8; ++i) {
      const bool t7 = (i == 7);
      const bool st = (!t7) || hn;             // tiles 2i+2 / 2i+3 exist
      const bool vlast = t7 && !hn;            // final K-tile of final segment
      const ushort* SA2 = t7 ? An : A; const int la2 = t7 ? ldan : lda;
      const ushort* SB2 = t7 ? Bn : B;
      const int k1 = (2 * i + 1) * 64;
      const int k2 = t7 ? 0 : (2 * i + 2) * 64;
      const int k3 = t7 ? 64 : (2 * i + 3) * 64;
      // P1: prefetch b1(T0); stage T1.Bh0 -> B1; MFMA T0.Q00(a0,b0)
      DS_B(b1, B0, 1);
      STAGE_HALF(B, 1024, col0, k1, B1, 0);
      MFMA_Q(0, 0, a0, b0);
      BAR();
      // P2: prefetch a1(T0); stage T1.Bh1 -> B1; MFMA T0.Q01(a0,b1)
      DS_A(a1, A0, 1);
      STAGE_HALF(B, 1024, col0, k1, B1, 1);
      MFMA_Q(0, 1, a0, b1);
      BAR();
      // P3: stage T2.Ah0 -> A0; MFMA T0.Q10(a1,b0); vm-guard for P4 reads
      if (st) { STAGE_HALF(SA2, la2, row0, k2, A0, 0); VMW(2); }
      else    { VMW(0); }
      MFMA_Q(1, 0, a1, b0);
      BAR();
      // P4: prefetch a0,b0 (T1 from A1/B1); stage T2.Ah1 -> A0; MFMA T0.Q11(a1,b1)
      DS_A(a0, A1, 0);
      DS_B(b0, B1, 0);
      if (st) STAGE_HALF(SA2, la2, row0, k2, A0, 1);
      MFMA_Q(1, 1, a1, b1);
      BAR();
      // P5: prefetch b1(T1); stage T2.Bh0 -> B0; MFMA T1.Q00(a0,b0)
      DS_B(b1, B1, 1);
      if (st) STAGE_HALF(SB2, 1024, col0, k2, B0, 0);
      MFMA_Q(0, 0, a0, b0);
      BAR();
      // P6: prefetch a1(T1); stage T2.Bh1 -> B0; MFMA T1.Q01(a0,b1)
      DS_A(a1, A1, 1);
      if (st) STAGE_HALF(SB2, 1024, col0, k2, B0, 1);
      MFMA_Q(0, 1, a1 /*dummy order fix below*/, b1);
      BAR();
      // NOTE: P6 must use a0 (T1 quad0 rows) -- corrected line is below; this
      // placeholder is never compiled (see real code path).
      // P7: stage T3.Ah0 -> A1; MFMA T1.Q10(a1,b0); vm-guard for P8 reads
      if (st) { STAGE_HALF(SA2 /*unused*/, la2, row0, k3, A1, 0); VMW(2); }
      else    { VMW(0); }
      MFMA_Q(1, 0, a1, b0);
      BAR();
      // P8: prefetch a0,b0 (T2 from A0/B0) unless very last; stage T3.Ah1 -> A1
      if (!vlast) { DS_A(a0, A0, 0); DS_B(b0, B0, 0); }
      if (st) STAGE_HALF(SA2, la2, row0, k3, A1, 1);
      MFMA_Q(1, 1, a1, b1);
      BAR();
    }
  }
}

// The P6 comment above flags an operand mistake; provide the real pipe used by
// kernels (P6 uses a0 with b1; A-stage pointer for T3 is SA3 = SA2 here since
// both tiles 2i+2 and 2i+3 come from the same segment source).
template<int NSEG>
__device__ __forceinline__ void gemm256_pipe_fixed(
    const ushort* const Aseg[], const int ldaseg[], const ushort* const Bseg[],
    ushort* lds, int row0, int col0, int w, int l,
    int wr, int wc, int lo, int c0us, int c1us, f32x4 (&acc)[8][4]) {
  ushort* A0 = lds;
  ushort* A1 = lds + 16384;
  ushort* B0 = lds + 32768;
  ushort* B1 = lds + 49152;
  bf16x8 a0[4][2], a1[4][2], b0[2][2], b1[2][2];

  {
    const ushort* A = Aseg[0]; const int lda = ldaseg[0];
    const ushort* B = Bseg[0];
    STAGE_HALF(A, lda, row0, 0, A0, 0);
    STAGE_HALF(A, lda, row0, 0, A0, 1);
    STAGE_HALF(B, 1024, col0, 0, B0, 0);
    STAGE_HALF(B, 1024, col0, 0, B0, 1);
    STAGE_HALF(A, lda, row0, 64, A1, 0);
    STAGE_HALF(A, lda, row0, 64, A1, 1);
    VMW(4);
    BAR();
    DS_A(a0, A0, 0);
    DS_B(b0, B0, 0);
  }

#pragma unroll
  for (int s = 0; s < NSEG; ++s) {
    const ushort* A = Aseg[s]; const int lda = ldaseg[s];
    const ushort* B = Bseg[s];
    const bool hn = (s + 1 < NSEG);
    const ushort* An = hn ? Aseg[s + 1] : (const ushort*)0;
    const int ldan = hn ? ldaseg[s + 1] : 0;
    const ushort* Bn = hn ? Bseg[s + 1] : (const ushort*)0;
#pragma unroll 1
    for (int i = 0; i < 8; ++i) {
      const bool t7 = (i == 7);
      const bool st = (!t7) || hn;
      const bool vlast = t7 && !hn;
      const ushort* SA2 = t7 ? An : A; const int la2 = t7 ? ldan : lda;
      const ushort* SB2 = t7 ? Bn : B;
      const int k1 = (2 * i + 1) * 64;
      const int k2 = t7 ? 0 : (2 * i + 2) * 64;
      const int k3 = t7 ? 64 : (2 * i + 3) * 64;
      // P1
      DS_B(b1, B0, 1);
      STAGE_HALF(B, 1024, col0, k1, B1, 0);
      MFMA_Q(0, 0, a0, b0);
      BAR();
      // P2
      DS_A(a1, A0, 1);
      STAGE_HALF(B, 1024, col0, k1, B1, 1);
      MFMA_Q(0, 1, a0, b1);
      BAR();
      // P3
      if (st) { STAGE_HALF(SA2, la2, row0, k2, A0, 0); VMW(2); }
      else    { VMW(0); }
      MFMA_Q(1, 0, a1, b0);
      BAR();
      // P4
      DS_A(a0, A1, 0);
      DS_B(b0, B1, 0);
      if (st) STAGE_HALF(SA2, la2, row0, k2, A0, 1);
      MFMA_Q(1, 1, a1, b1);
      BAR();
      // P5
      DS_B(b1, B1, 1);
      if (st) STAGE_HALF(SB2, 1024, col0, k2, B0, 0);
      MFMA_Q(0, 0, a0, b0);
      BAR();
      // P6
      DS_A(a1, A1, 1);
      if (st) STAGE_HALF(SB2, 1024, col0, k2, B0, 1);
      MFMA_Q(0, 1, a0, b1);
      BAR();
      // P7
      if (st) { STAGE_HALF(SA2, la2, row0, k3, A1, 0); VMW(2); }
      else    { VMW(0); }
      MFMA_Q(1, 0, a1, b0);
      BAR();
      // P8
      if (!vlast) { DS_A(a0, A0, 0); DS_B(b0, B0, 0); }
      if (st) STAGE_HALF(SA2, la2, row0, k3, A1, 1);
      MFMA_Q(1, 1, a1, b1);
      BAR();
    }
  }
}

// ---------------- Bu GEMM: X @ [BreT;BimT]^T -> bf16 T x 2048 ----------------
__global__ __launch_bounds__(512, 2) void gemm_bu(
    const ushort* __restrict__ A, const ushort* __restrict__ B,
    ushort* __restrict__ O) {
  __shared__ __align__(16) ushort lds[65536];
  const int tid = threadIdx.x;
  const int w = tid >> 6, l = tid & 63;
  const int wr = w >> 2, wc = w & 3;
  const int lo = l & 15, q = l >> 4;
  const int xorv = (lo & 7) << 4;
  const int c0us = ((q * 16) ^ xorv) >> 1;
  const int c1us = ((64 + q * 16) ^ xorv) >> 1;
  // XCD-grouped mapping: each XCD owns 8 contiguous row-panels x all 8 col-panels
  const int id = blockIdx.x;
  const int xcd = id & 7, slot = id >> 3;
  const int row0 = (xcd * 8 + (slot >> 3)) * 256;
  const int col0 = (slot & 7) * 256;
  f32x4 acc[8][4];
#pragma unroll
  for (int m = 0; m < 8; ++m)
#pragma unroll
    for (int n = 0; n < 4; ++n) acc[m][n] = (f32x4){0.f, 0.f, 0.f, 0.f};
  const ushort* Aseg[1] = {A};
  const int     ldas[1] = {1024};
  const ushort* Bseg[1] = {B};
  gemm256_pipe_fixed<1>(Aseg, ldas, Bseg, lds, row0, col0, w, l, wr, wc, lo,
                        c0us, c1us, acc);
  const int rowb = row0 + wr * 128, colb = col0 + wc * 64;
#pragma unroll
  for (int m = 0; m < 8; ++m)
#pragma unroll
    for (int n = 0; n < 4; ++n) {
      int col = colb + n * 16 + lo;
#pragma unroll
      for (int r = 0; r < 4; ++r)
        O[(size_t)(rowb + m * 16 + q * 4 + r) * 2048 + col] = f2bf(acc[m][n][r]);
    }
}

// ---------------- out = Hre@Cre^T + Him@(-Cim)^T + X@D^T ----------------
__global__ __launch_bounds__(512, 2) void gemm3(
    const ushort* __restrict__ Hall,
    const ushort* __restrict__ CreB, const ushort* __restrict__ CimB,
    const ushort* __restrict__ X,    const ushort* __restrict__ DT,
    float* __restrict__ O) {
  __shared__ __align__(16) ushort lds[65536];
  const int tid = threadIdx.x;
  const int w = tid >> 6, l = tid & 63;
  const int wr = w >> 2, wc = w & 3;
  const int lo = l & 15, q = l >> 4;
  const int xorv = (lo & 7) << 4;
  const int c0us = ((q * 16) ^ xorv) >> 1;
  const int c1us = ((64 + q * 16) ^ xorv) >> 1;
  // XCD-grouped mapping: each XCD owns 8 contiguous row-panels x all 4 col-panels
  const int id = blockIdx.x;
  const int xcd = id & 7, slot = id >> 3;
  const int row0 = (xcd * 8 + (slot >> 2)) * 256;
  const int col0 = (slot & 3) * 256;
  f32x4 acc[8][4];
#pragma unroll
  for (int m = 0; m < 8; ++m)
#pragma unroll
    for (int n = 0; n < 4; ++n) acc[m][n] = (f32x4){0.f, 0.f, 0.f, 0.f};
  const ushort* Aseg[3] = {Hall, Hall + 1024, X};
  const int     ldas[3] = {2048, 2048, 1024};
  const ushort* Bseg[3] = {CreB, CimB, DT};
  gemm256_pipe_fixed<3>(Aseg, ldas, Bseg, lds, row0, col0, w, l, wr, wc, lo,
                        c0us, c1us, acc);
  const int rowb = row0 + wr * 128, colb = col0 + wc * 64;
#pragma unroll
  for (int m = 0; m < 8; ++m)
#pragma unroll
    for (int n = 0; n < 4; ++n) {
      int col = colb + n * 16 + lo;
#pragma unroll
      for (int r = 0; r < 4; ++r)
        O[(size_t)(rowb + m * 16 + q * 4 + r) * HID + col] = acc[m][n][r];
    }
}

// ---------------- scan pass A: chunk sums only (Bu: T x 2048 bf16) -------------
__global__ __launch_bounds__(256) void scan_sums(
    const ushort* __restrict__ Bu,
    const float* __restrict__ lam_re, const float* __restrict__ lam_im,
    float* __restrict__ Sre, float* __restrict__ Sim) {
  int h0 = (blockIdx.y * 256 + threadIdx.x) * 2;
  int c = blockIdx.x;
  float lr0 = lam_re[h0], li0 = lam_im[h0];
  float lr1 = lam_re[h0 + 1], li1 = lam_im[h0 + 1];
  float hr0 = 0.f, hi0 = 0.f, hr1 = 0.f, hi1 = 0.f;
  const uint* P = (const uint*)Bu;
  size_t baseR = (size_t)c * CHUNK * 1024 + (h0 >> 1);
  size_t baseI = baseR + 512;
#pragma unroll 8
  for (int t = 0; t < CHUNK; ++t) {
    uint re = P[baseR + (size_t)t * 1024];
    uint im = P[baseI + (size_t)t * 1024];
    float br0 = bf2f((ushort)re), br1 = bf2f((ushort)(re >> 16));
    float bi0 = bf2f((ushort)im), bi1 = bf2f((ushort)(im >> 16));
    float nr0 = fmaf(lr0, hr0, fmaf(-li0, hi0, br0));
    float ni0 = fmaf(lr0, hi0, fmaf(li0, hr0, bi0));
    float nr1 = fmaf(lr1, hr1, fmaf(-li1, hi1, br1));
    float ni1 = fmaf(lr1, hi1, fmaf(li1, hr1, bi1));
    hr0 = nr0; hi0 = ni0; hr1 = nr1; hi1 = ni1;
  }
  Sre[(size_t)c * HID + h0] = hr0;  Sre[(size_t)c * HID + h0 + 1] = hr1;
  Sim[(size_t)c * HID + h0] = hi0;  Sim[(size_t)c * HID + h0 + 1] = hi1;
}

// ---------------- scan pass 2: serial carry scan over chunks ----------------
__global__ __launch_bounds__(256) void scan_carry(
    const float* __restrict__ Sre, const float* __restrict__ Sim,
    const float* __restrict__ lam_re, const float* __restrict__ lam_im,
    float* __restrict__ Pre, float* __restrict__ Pim) {
  int h = blockIdx.x * 256 + threadIdx.x;
  float lr = lam_re[h], li = lam_im[h];
  float pr = lr, pi = li;
#pragma unroll
  for (int s = 0; s < 6; ++s) {
    float nr = pr * pr - pi * pi;
    float ni = 2.f * pr * pi;
    pr = nr; pi = ni;
  }
  float cr = 0.f, ci = 0.f;
  for (int c = 0; c < NCHUNK; ++c) {
    Pre[(size_t)c * HID + h] = cr;
    Pim[(size_t)c * HID + h] = ci;
    float sr = Sre[(size_t)c * HID + h];
    float si = Sim[(size_t)c * HID + h];
    float nr = fmaf(pr, cr, fmaf(-pi, ci, sr));
    float ni = fmaf(pr, ci, fmaf(pi, cr, si));
    cr = nr; ci = ni;
  }
}

// ---------------- scan pass B: replay with carry init, emit bf16 Hall ----------
__global__ __launch_bounds__(256) void scan_emit(
    const ushort* __restrict__ Bu,
    const float* __restrict__ lam_re, const float* __restrict__ lam_im,
    const float* __restrict__ Pre, const float* __restrict__ Pim,
    ushort* __restrict__ Hall) {
  int h0 = (blockIdx.y * 256 + threadIdx.x) * 2;
  int c = blockIdx.x;
  float lr0 = lam_re[h0], li0 = lam_im[h0];
  float lr1 = lam_re[h0 + 1], li1 = lam_im[h0 + 1];
  float hr0 = Pre[(size_t)c * HID + h0], hi0 = Pim[(size_t)c * HID + h0];
  float hr1 = Pre[(size_t)c * HID + h0 + 1], hi1 = Pim[(size_t)c * HID + h0 + 1];
  const uint* P = (const uint*)Bu;
  uint* Q = (uint*)Hall;
  size_t baseR = (size_t)c * CHUNK * 1024 + (h0 >> 1);
  size_t baseI = baseR + 512;
#pragma unroll 8
  for (int t = 0; t < CHUNK; ++t) {
    uint re = P[baseR + (size_t)t * 1024];
    uint im = P[baseI + (size_t)t * 1024];
    float br0 = bf2f((ushort)re), br1 = bf2f((ushort)(re >> 16));
    float bi0 = bf2f((ushort)im), bi1 = bf2f((ushort)(im >> 16));
    float nr0 = fmaf(lr0, hr0, fmaf(-li0, hi0, br0));
    float ni0 = fmaf(lr0, hi0, fmaf(li0, hr0, bi0));
    float nr1 = fmaf(lr1, hr1, fmaf(-li1, hi1, br1));
    float ni1 = fmaf(lr1, hi1, fmaf(li1, hr1, bi1));
    hr0 = nr0; hi0 = ni0; hr1 = nr1; hi1 = ni1;
    Q[baseR + (size_t)t * 1024] = (uint)f2bf(hr0) | ((uint)f2bf(hr1) << 16);
    Q[baseI + (size_t)t * 1024] = (uint)f2bf(hi0) | ((uint)f2bf(hi1) << 16);
  }
}

extern "C" void kernel_launch(void* const* d_in, const int* in_sizes, int n_in,
                              void* d_out, int out_size, void* d_ws, size_t ws_size,
                              hipStream_t stream) {
  const float* inputs    = (const float*)d_in[0];
  const float* nu_log    = (const float*)d_in[1];
  const float* theta_log = (const float*)d_in[2];
  const float* gamma_log = (const float*)d_in[3];
  const float* B_re      = (const float*)d_in[4];
  const float* B_im      = (const float*)d_in[5];
  const float* C_re      = (const float*)d_in[6];
  const float* C_im      = (const float*)d_in[7];
  const float* D         = (const float*)d_in[8];
  float* out = (float*)d_out;

  char* ws = (char*)d_ws;
  constexpr size_t TH = (size_t)T_LEN * HID;       // 16.8M
  constexpr size_t W  = (size_t)1024 * 1024;
  constexpr size_t CH = (size_t)NCHUNK * HID;

  ushort* Xbf  = (ushort*)(ws);                    // TH*2
  ushort* Bu   = (ushort*)(ws + TH * 2);           // TH*2*2 (T x 2048)
  ushort* Hall = (ushort*)(ws + TH * 6);           // TH*2*2 (T x 2048)
  char*   p    = ws + TH * 10;
  ushort* Ball = (ushort*)(p);             p += 2 * W * 2;   // [BreT; BimT]
  ushort* CreB = (ushort*)(p);             p += W * 2;
  ushort* CimB = (ushort*)(p);             p += W * 2;
  ushort* DT   = (ushort*)(p);             p += W * 2;
  float*  Sre  = (float*)(p);              p += CH * 4;
  float*  Sim  = (float*)(p);              p += CH * 4;
  float*  Pre  = (float*)(p);              p += CH * 4;
  float*  Pim  = (float*)(p);              p += CH * 4;
  float*  lamR = (float*)(p);              p += 4096;
  float*  lamI = (float*)(p);              p += 4096;
  float*  eg   = (float*)(p);              p += 4096;
  ushort* BreT = Ball;
  ushort* BimT = Ball + W;

  prep_kernel<<<dim3(HID / 256), 256, 0, stream>>>(nu_log, theta_log, gamma_log,
                                                   lamR, lamI, eg);
  convX<<<dim3((unsigned)(TH / 4 / 256)), 256, 0, stream>>>(inputs, Xbf);
  weight_prep<<<dim3(32, 32, 5), 256, 0, stream>>>(B_re, B_im, C_re, C_im, D, eg,
                                                   BreT, BimT, CreB, CimB, DT);

  gemm_bu<<<dim3(512), 512, 0, stream>>>(Xbf, Ball, Bu);

  scan_sums<<<dim3(NCHUNK, HID / 512), 256, 0, stream>>>(Bu, lamR, lamI, Sre, Sim);
  scan_carry<<<dim3(HID / 256), 256, 0, stream>>>(Sre, Sim, lamR, lamI, Pre, Pim);
  scan_emit<<<dim3(NCHUNK, HID / 512), 256, 0, stream>>>(Bu, lamR, lamI, Pre, Pim,
                                                         Hall);

  gemm3<<<dim3(256), 512, 0, stream>>>(Hall, CreB, CimB, Xbf, DT, out);
}

// Round 3
// 354.501 us; speedup vs baseline: 1.5998x; 1.5998x over previous
//
#include <hip/hip_runtime.h>
#include <hip/hip_bf16.h>
#include <stdint.h>

#define T_LEN   16384
#define HID     1024
#define KDIM    1024
#define CHUNK   64
#define NCHUNK  256   // T_LEN / CHUNK

typedef __bf16 bf16x8 __attribute__((ext_vector_type(8)));
typedef float  f32x4  __attribute__((ext_vector_type(4)));

__device__ inline ushort f2bf(float f) {
  union { float f; uint32_t u; } v; v.f = f;
  uint32_t r = v.u + 0x7FFF + ((v.u >> 16) & 1);   // RNE
  return (ushort)(r >> 16);
}
__device__ inline float bf2f(ushort u) {
  union { uint32_t u; float f; } v; v.u = ((uint32_t)u) << 16;
  return v.f;
}

__device__ inline void gload16(const void* g, void* l) {
  __builtin_amdgcn_global_load_lds(
      (const __attribute__((address_space(1))) void*)g,
      (__attribute__((address_space(3))) void*)l, 16, 0, 0);
}

// ---------------- prep: lambda (complex), exp(gamma) ----------------
__global__ __launch_bounds__(256) void prep_kernel(
    const float* __restrict__ nu_log, const float* __restrict__ theta_log,
    const float* __restrict__ gamma_log,
    float* __restrict__ lam_re, float* __restrict__ lam_im, float* __restrict__ eg) {
  int h = blockIdx.x * 256 + threadIdx.x;
  if (h < HID) {
    float mag = expf(-expf(nu_log[h]));
    float th  = expf(theta_log[h]);
    lam_re[h] = mag * cosf(th);
    lam_im[h] = mag * sinf(th);
    eg[h]     = expf(gamma_log[h]);
  }
}

// ---------------- fp32 -> bf16, vectorized x4 ----------------
__global__ __launch_bounds__(256) void convX(
    const float* __restrict__ src, ushort* __restrict__ dst) {
  size_t i = ((size_t)blockIdx.x * 256 + threadIdx.x) * 4;
  float4 v = *(const float4*)(src + i);
  ushort4 o;
  o.x = f2bf(v.x); o.y = f2bf(v.y); o.z = f2bf(v.z); o.w = f2bf(v.w);
  *(ushort4*)(dst + i) = o;
}

// ---------------- all weight prep in one kernel (z selects job) ----------------
__global__ __launch_bounds__(256) void weight_prep(
    const float* __restrict__ Bre, const float* __restrict__ Bim,
    const float* __restrict__ Cre, const float* __restrict__ Cim,
    const float* __restrict__ D,   const float* __restrict__ eg,
    ushort* __restrict__ BreT, ushort* __restrict__ BimT,
    ushort* __restrict__ CreB, ushort* __restrict__ CimB,
    ushort* __restrict__ DT) {
  __shared__ float tile[32][33];
  int z = blockIdx.z;
  if (z == 2 || z == 3) {
    const float* src = (z == 2) ? Cre : Cim;
    ushort* dst = (z == 2) ? CreB : CimB;
    float s = (z == 2) ? 1.0f : -1.0f;
    size_t base = ((size_t)blockIdx.y * 32 + (threadIdx.x >> 3)) * 1024 +
                  blockIdx.x * 32 + (threadIdx.x & 7) * 4;
    float4 v = *(const float4*)(src + base);
    ushort4 o;
    o.x = f2bf(v.x * s); o.y = f2bf(v.y * s);
    o.z = f2bf(v.z * s); o.w = f2bf(v.w * s);
    *(ushort4*)(dst + base) = o;
    return;
  }
  const float* src = (z == 0) ? Bre : (z == 1) ? Bim : D;
  ushort* dst = (z == 0) ? BreT : (z == 1) ? BimT : DT;
  bool scaled = (z < 2);
  int bx = blockIdx.x * 32;   // n-block
  int by = blockIdx.y * 32;   // k-block
  int tx = threadIdx.x & 31, ty = threadIdx.x >> 5;
#pragma unroll
  for (int r = 0; r < 32; r += 8)
    tile[ty + r][tx] = src[(size_t)(by + ty + r) * 1024 + bx + tx];
  __syncthreads();
  float sc = scaled ? eg[by + tx] : 1.0f;
#pragma unroll
  for (int r = 0; r < 32; r += 8)
    dst[(size_t)(bx + ty + r) * 1024 + by + tx] = f2bf(tile[tx][ty + r] * sc);
}

// ================= 256x256 8-phase MFMA GEMM (m201 template shape) =============
// 512 threads = 8 waves (2 M x 4 N). Per-wave output 128x64.
// LDS: A dbuf 2x[256][64] + B dbuf 2x[256][64] bf16 = 128 KiB.
// Per phase: ds_read fragments -> stage next half-tile -> BAR -> lgkmcnt(0) ->
// sched_barrier(0) [rule 18] -> setprio(1) MFMA setprio(0) -> BAR.
// NO phase-end sched_barrier (m141): compiler may hoist next-phase ds_read/addr
// VALU into the MFMA shadow where register WAR allows.
// vmcnt(4) at P4/P8: guarantees the half-tiles consumed by the NEXT phase's
// ds_reads have landed; 4 loads stay in flight across barriers.

#define BAR()   __builtin_amdgcn_s_barrier()
#define SCH0()  __builtin_amdgcn_sched_barrier(0)
#define LGKM0() asm volatile("s_waitcnt lgkmcnt(0)")
#define VM4()   asm volatile("s_waitcnt vmcnt(4)")
#define VM0()   asm volatile("s_waitcnt vmcnt(0)")

#define STAGE_HALF(G, LDA, R0, K0, LT, HALF)                         \
  do {                                                               \
    _Pragma("unroll")                                                \
    for (int is_ = 0; is_ < 2; ++is_) {                              \
      int seg_ = w * 2 + is_;                                        \
      int gr_ = (R0) + (HALF) * 128 + seg_ * 8 + (l >> 3);           \
      int gc_ = (K0) + (((l & 7) ^ (l >> 3)) << 3);                  \
      gload16((G) + (size_t)gr_ * (LDA) + gc_,                       \
              (LT) + (HALF) * 8192 + seg_ * 512);                    \
    }                                                                \
  } while (0)

#define DS_A(QM, BUF)                                                \
  do {                                                               \
    _Pragma("unroll")                                                \
    for (int m_ = 0; m_ < 4; ++m_) {                                 \
      int r_ = (wr * 128 + ((QM) * 4 + m_) * 16 + lo) * 64;          \
      a[m_][0] = *(const bf16x8*)((BUF) + r_ + c0us);                \
      a[m_][1] = *(const bf16x8*)((BUF) + r_ + c1us);                \
    }                                                                \
  } while (0)

#define DS_B(QN, BUF, REG)                                           \
  do {                                                               \
    _Pragma("unroll")                                                \
    for (int n_ = 0; n_ < 2; ++n_) {                                 \
      int r_ = (wc * 64 + ((QN) * 2 + n_) * 16 + lo) * 64;           \
      REG[n_][0] = *(const bf16x8*)((BUF) + r_ + c0us);              \
      REG[n_][1] = *(const bf16x8*)((BUF) + r_ + c1us);              \
    }                                                                \
  } while (0)

#define MFMA_Q(QM, QN, REG)                                          \
  do {                                                               \
    __builtin_amdgcn_s_setprio(1);                                   \
    _Pragma("unroll")                                                \
    for (int m_ = 0; m_ < 4; ++m_)                                   \
      _Pragma("unroll")                                              \
      for (int n_ = 0; n_ < 2; ++n_) {                               \
        f32x4* ac_ = &acc[(QM) * 4 + m_][(QN) * 2 + n_];             \
        *ac_ = __builtin_amdgcn_mfma_f32_16x16x32_bf16(              \
            a[m_][0], REG[n_][0], *ac_, 0, 0, 0);                    \
        *ac_ = __builtin_amdgcn_mfma_f32_16x16x32_bf16(              \
            a[m_][1], REG[n_][1], *ac_, 0, 0, 0);                    \
      }                                                              \
    __builtin_amdgcn_s_setprio(0);                                   \
  } while (0)

// K is fixed 1024 (16 k-tiles of 64, 8 iterations x 8 phases).
__device__ __forceinline__ void gemm256_seg(
    const ushort* __restrict__ A, int lda, const ushort* __restrict__ B,
    ushort* lds, int row0, int col0,
    int w, int l, int wr, int wc, int lo, int q, int c0us, int c1us,
    f32x4 acc[8][4]) {
  ushort* A0 = lds;
  ushort* A1 = lds + 16384;
  ushort* B0 = lds + 32768;
  ushort* B1 = lds + 49152;
  bf16x8 a[4][2], bq0[2][2], bq1[2][2];
  // prologue: tile0 (A+B) -> buf0, tile1 B -> buf1
  STAGE_HALF(A, lda, row0, 0, A0, 0);
  STAGE_HALF(A, lda, row0, 0, A0, 1);
  STAGE_HALF(B, 1024, col0, 0, B0, 0);
  STAGE_HALF(B, 1024, col0, 0, B0, 1);
  STAGE_HALF(B, 1024, col0, 64, B1, 0);
  STAGE_HALF(B, 1024, col0, 64, B1, 1);
  VM4(); BAR();
  for (int i = 0; i < 8; ++i) {
    const int k1 = (2 * i + 1) * 64;
    const int k2 = (2 * i + 2) * 64;
    const int k3 = (2 * i + 3) * 64;
    const bool st2 = (i < 7);   // tiles 2i+2 / 2i+3 exist
    // ---- tile 2i from buf0 ----
    // P1
    DS_A(0, A0); DS_B(0, B0, bq0);
    STAGE_HALF(A, lda, row0, k1, A1, 0);
    BAR(); LGKM0(); SCH0(); MFMA_Q(0, 0, bq0); BAR();
    // P2
    DS_B(1, B0, bq1);
    STAGE_HALF(A, lda, row0, k1, A1, 1);
    BAR(); LGKM0(); SCH0(); MFMA_Q(0, 1, bq1); BAR();
    // P3
    DS_A(1, A0);
    if (st2) STAGE_HALF(B, 1024, col0, k2, B0, 0);
    BAR(); LGKM0(); SCH0(); MFMA_Q(1, 0, bq0); BAR();
    // P4
    if (st2) { STAGE_HALF(B, 1024, col0, k2, B0, 1); VM4(); } else { VM0(); }
    BAR(); LGKM0(); SCH0(); MFMA_Q(1, 1, bq1); BAR();
    // ---- tile 2i+1 from buf1 ----
    // P5
    DS_A(0, A1); DS_B(0, B1, bq0);
    if (st2) STAGE_HALF(A, lda, row0, k2, A0, 0);
    BAR(); LGKM0(); SCH0(); MFMA_Q(0, 0, bq0); BAR();
    // P6
    DS_B(1, B1, bq1);
    if (st2) STAGE_HALF(A, lda, row0, k2, A0, 1);
    BAR(); LGKM0(); SCH0(); MFMA_Q(0, 1, bq1); BAR();
    // P7
    DS_A(1, A1);
    if (st2) STAGE_HALF(B, 1024, col0, k3, B1, 0);
    BAR(); LGKM0(); SCH0(); MFMA_Q(1, 0, bq0); BAR();
    // P8
    if (st2) { STAGE_HALF(B, 1024, col0, k3, B1, 1); VM4(); } else { VM0(); }
    BAR(); LGKM0(); SCH0(); MFMA_Q(1, 1, bq1); BAR();
  }
}

// ---------------- Bu GEMM: X @ [BreT;BimT]^T -> bf16 T x 2048 ----------------
__global__ __launch_bounds__(512, 2) void gemm_bu(
    const ushort* __restrict__ A, const ushort* __restrict__ B,
    ushort* __restrict__ O) {
  __shared__ __align__(16) ushort lds[65536];
  const int tid = threadIdx.x;
  const int w = tid >> 6, l = tid & 63;
  const int wr = w >> 2, wc = w & 3;
  const int lo = l & 15, q = l >> 4;
  const int xorv = (lo & 7) << 4;
  const int c0us = ((q * 16) ^ xorv) >> 1;
  const int c1us = ((64 + q * 16) ^ xorv) >> 1;
  // XCD-grouped mapping (round-robin id%8 -> XCD): XCD x owns row-panels
  // [8x, 8x+8) x all 8 col-panels -> A-panel readers co-resident on one L2.
  const int id = blockIdx.x;
  const int xcd = id & 7, slot = id >> 3;
  const int row0 = (xcd * 8 + (slot >> 3)) * 256;
  const int col0 = (slot & 7) * 256;
  f32x4 acc[8][4];
#pragma unroll
  for (int m = 0; m < 8; ++m)
#pragma unroll
    for (int n = 0; n < 4; ++n) acc[m][n] = (f32x4){0.f, 0.f, 0.f, 0.f};
  gemm256_seg(A, 1024, B, lds, row0, col0, w, l, wr, wc, lo, q, c0us, c1us, acc);
  const int rowb = row0 + wr * 128, colb = col0 + wc * 64;
#pragma unroll
  for (int m = 0; m < 8; ++m)
#pragma unroll
    for (int n = 0; n < 4; ++n) {
      int col = colb + n * 16 + lo;
#pragma unroll
      for (int r = 0; r < 4; ++r)
        O[(size_t)(rowb + m * 16 + q * 4 + r) * 2048 + col] = f2bf(acc[m][n][r]);
    }
}

// ---------------- out = Hre@Cre^T + Him@(-Cim)^T + X@D^T ----------------
__global__ __launch_bounds__(512, 2) void gemm3(
    const ushort* __restrict__ Hall,
    const ushort* __restrict__ CreB, const ushort* __restrict__ CimB,
    const ushort* __restrict__ X,    const ushort* __restrict__ DT,
    float* __restrict__ O) {
  __shared__ __align__(16) ushort lds[65536];
  const int tid = threadIdx.x;
  const int w = tid >> 6, l = tid & 63;
  const int wr = w >> 2, wc = w & 3;
  const int lo = l & 15, q = l >> 4;
  const int xorv = (lo & 7) << 4;
  const int c0us = ((q * 16) ^ xorv) >> 1;
  const int c1us = ((64 + q * 16) ^ xorv) >> 1;
  // XCD-grouped mapping: XCD x owns row-panels [8x, 8x+8) x all 4 col-panels.
  const int id = blockIdx.x;
  const int xcd = id & 7, slot = id >> 3;
  const int row0 = (xcd * 8 + (slot >> 2)) * 256;
  const int col0 = (slot & 3) * 256;
  f32x4 acc[8][4];
#pragma unroll
  for (int m = 0; m < 8; ++m)
#pragma unroll
    for (int n = 0; n < 4; ++n) acc[m][n] = (f32x4){0.f, 0.f, 0.f, 0.f};
  gemm256_seg(Hall,        2048, CreB, lds, row0, col0, w, l, wr, wc, lo, q, c0us, c1us, acc);
  gemm256_seg(Hall + 1024, 2048, CimB, lds, row0, col0, w, l, wr, wc, lo, q, c0us, c1us, acc);
  gemm256_seg(X,           1024, DT,   lds, row0, col0, w, l, wr, wc, lo, q, c0us, c1us, acc);
  const int rowb = row0 + wr * 128, colb = col0 + wc * 64;
#pragma unroll
  for (int m = 0; m < 8; ++m)
#pragma unroll
    for (int n = 0; n < 4; ++n) {
      int col = colb + n * 16 + lo;
#pragma unroll
      for (int r = 0; r < 4; ++r)
        O[(size_t)(rowb + m * 16 + q * 4 + r) * HID + col] = acc[m][n][r];
    }
}

// ---------------- scan pass A: chunk sums only (Bu: T x 2048 bf16) -------------
__global__ __launch_bounds__(256) void scan_sums(
    const ushort* __restrict__ Bu,
    const float* __restrict__ lam_re, const float* __restrict__ lam_im,
    float* __restrict__ Sre, float* __restrict__ Sim) {
  int h0 = (blockIdx.y * 256 + threadIdx.x) * 2;
  int c = blockIdx.x;
  float lr0 = lam_re[h0], li0 = lam_im[h0];
  float lr1 = lam_re[h0 + 1], li1 = lam_im[h0 + 1];
  float hr0 = 0.f, hi0 = 0.f, hr1 = 0.f, hi1 = 0.f;
  const uint* P = (const uint*)Bu;
  size_t baseR = (size_t)c * CHUNK * 1024 + (h0 >> 1);          // uint idx, row stride 1024
  size_t baseI = baseR + 512;
#pragma unroll 8
  for (int t = 0; t < CHUNK; ++t) {
    uint re = P[baseR + (size_t)t * 1024];
    uint im = P[baseI + (size_t)t * 1024];
    float br0 = bf2f((ushort)re), br1 = bf2f((ushort)(re >> 16));
    float bi0 = bf2f((ushort)im), bi1 = bf2f((ushort)(im >> 16));
    float nr0 = fmaf(lr0, hr0, fmaf(-li0, hi0, br0));
    float ni0 = fmaf(lr0, hi0, fmaf(li0, hr0, bi0));
    float nr1 = fmaf(lr1, hr1, fmaf(-li1, hi1, br1));
    float ni1 = fmaf(lr1, hi1, fmaf(li1, hr1, bi1));
    hr0 = nr0; hi0 = ni0; hr1 = nr1; hi1 = ni1;
  }
  Sre[(size_t)c * HID + h0] = hr0;  Sre[(size_t)c * HID + h0 + 1] = hr1;
  Sim[(size_t)c * HID + h0] = hi0;  Sim[(size_t)c * HID + h0 + 1] = hi1;
}

// ---------------- scan pass 2: serial carry scan over chunks ----------------
__global__ __launch_bounds__(256) void scan_carry(
    const float* __restrict__ Sre, const float* __restrict__ Sim,
    const float* __restrict__ lam_re, const float* __restrict__ lam_im,
    float* __restrict__ Pre, float* __restrict__ Pim) {
  int h = blockIdx.x * 256 + threadIdx.x;
  float lr = lam_re[h], li = lam_im[h];
  float pr = lr, pi = li;       // lambda^64 via 6 squarings
#pragma unroll
  for (int s = 0; s < 6; ++s) {
    float nr = pr * pr - pi * pi;
    float ni = 2.f * pr * pi;
    pr = nr; pi = ni;
  }
  float cr = 0.f, ci = 0.f;
  for (int c = 0; c < NCHUNK; ++c) {
    Pre[(size_t)c * HID + h] = cr;
    Pim[(size_t)c * HID + h] = ci;
    float sr = Sre[(size_t)c * HID + h];
    float si = Sim[(size_t)c * HID + h];
    float nr = fmaf(pr, cr, fmaf(-pi, ci, sr));
    float ni = fmaf(pr, ci, fmaf(pi, cr, si));
    cr = nr; ci = ni;
  }
}

// ---------------- scan pass B: replay with carry init, emit bf16 Hall ----------
__global__ __launch_bounds__(256) void scan_emit(
    const ushort* __restrict__ Bu,
    const float* __restrict__ lam_re, const float* __restrict__ lam_im,
    const float* __restrict__ Pre, const float* __restrict__ Pim,
    ushort* __restrict__ Hall) {
  int h0 = (blockIdx.y * 256 + threadIdx.x) * 2;
  int c = blockIdx.x;
  float lr0 = lam_re[h0], li0 = lam_im[h0];
  float lr1 = lam_re[h0 + 1], li1 = lam_im[h0 + 1];
  float hr0 = Pre[(size_t)c * HID + h0], hi0 = Pim[(size_t)c * HID + h0];
  float hr1 = Pre[(size_t)c * HID + h0 + 1], hi1 = Pim[(size_t)c * HID + h0 + 1];
  const uint* P = (const uint*)Bu;
  uint* Q = (uint*)Hall;
  size_t baseR = (size_t)c * CHUNK * 1024 + (h0 >> 1);
  size_t baseI = baseR + 512;
#pragma unroll 8
  for (int t = 0; t < CHUNK; ++t) {
    uint re = P[baseR + (size_t)t * 1024];
    uint im = P[baseI + (size_t)t * 1024];
    float br0 = bf2f((ushort)re), br1 = bf2f((ushort)(re >> 16));
    float bi0 = bf2f((ushort)im), bi1 = bf2f((ushort)(im >> 16));
    float nr0 = fmaf(lr0, hr0, fmaf(-li0, hi0, br0));
    float ni0 = fmaf(lr0, hi0, fmaf(li0, hr0, bi0));
    float nr1 = fmaf(lr1, hr1, fmaf(-li1, hi1, br1));
    float ni1 = fmaf(lr1, hi1, fmaf(li1, hr1, bi1));
    hr0 = nr0; hi0 = ni0; hr1 = nr1; hi1 = ni1;
    Q[baseR + (size_t)t * 1024] = (uint)f2bf(hr0) | ((uint)f2bf(hr1) << 16);
    Q[baseI + (size_t)t * 1024] = (uint)f2bf(hi0) | ((uint)f2bf(hi1) << 16);
  }
}

extern "C" void kernel_launch(void* const* d_in, const int* in_sizes, int n_in,
                              void* d_out, int out_size, void* d_ws, size_t ws_size,
                              hipStream_t stream) {
  const float* inputs    = (const float*)d_in[0];
  const float* nu_log    = (const float*)d_in[1];
  const float* theta_log = (const float*)d_in[2];
  const float* gamma_log = (const float*)d_in[3];
  const float* B_re      = (const float*)d_in[4];
  const float* B_im      = (const float*)d_in[5];
  const float* C_re      = (const float*)d_in[6];
  const float* C_im      = (const float*)d_in[7];
  const float* D         = (const float*)d_in[8];
  float* out = (float*)d_out;

  char* ws = (char*)d_ws;
  constexpr size_t TH = (size_t)T_LEN * HID;       // 16.8M
  constexpr size_t W  = (size_t)1024 * 1024;
  constexpr size_t CH = (size_t)NCHUNK * HID;

  ushort* Xbf  = (ushort*)(ws);                    // TH*2
  ushort* Bu   = (ushort*)(ws + TH * 2);           // TH*2*2 (T x 2048)
  ushort* Hall = (ushort*)(ws + TH * 6);           // TH*2*2 (T x 2048)
  char*   p    = ws + TH * 10;
  ushort* Ball = (ushort*)(p);             p += 2 * W * 2;   // [BreT; BimT]
  ushort* CreB = (ushort*)(p);             p += W * 2;
  ushort* CimB = (ushort*)(p);             p += W * 2;
  ushort* DT   = (ushort*)(p);             p += W * 2;
  float*  Sre  = (float*)(p);              p += CH * 4;
  float*  Sim  = (float*)(p);              p += CH * 4;
  float*  Pre  = (float*)(p);              p += CH * 4;
  float*  Pim  = (float*)(p);              p += CH * 4;
  float*  lamR = (float*)(p);              p += 4096;
  float*  lamI = (float*)(p);              p += 4096;
  float*  eg   = (float*)(p);              p += 4096;
  ushort* BreT = Ball;
  ushort* BimT = Ball + W;

  prep_kernel<<<dim3(HID / 256), 256, 0, stream>>>(nu_log, theta_log, gamma_log,
                                                   lamR, lamI, eg);
  convX<<<dim3((unsigned)(TH / 4 / 256)), 256, 0, stream>>>(inputs, Xbf);
  weight_prep<<<dim3(32, 32, 5), 256, 0, stream>>>(B_re, B_im, C_re, C_im, D, eg,
                                                   BreT, BimT, CreB, CimB, DT);

  gemm_bu<<<dim3(512), 512, 0, stream>>>(Xbf, Ball, Bu);

  scan_sums<<<dim3(NCHUNK, HID / 512), 256, 0, stream>>>(Bu, lamR, lamI, Sre, Sim);
  scan_carry<<<dim3(HID / 256), 256, 0, stream>>>(Sre, Sim, lamR, lamI, Pre, Pim);
  scan_emit<<<dim3(NCHUNK, HID / 512), 256, 0, stream>>>(Bu, lamR, lamI, Pre, Pim,
                                                         Hall);

  gemm3<<<dim3(256), 512, 0, stream>>>(Hall, CreB, CimB, Xbf, DT, out);
}

// Round 5
// 340.868 us; speedup vs baseline: 1.6638x; 1.0400x over previous
//
#include <hip/hip_runtime.h>
#include <hip/hip_bf16.h>
#include <stdint.h>

#define T_LEN   16384
#define HID     1024
#define KDIM    1024
#define CHUNK   64
#define NCHUNK  256   // T_LEN / CHUNK

typedef __bf16 bf16x8 __attribute__((ext_vector_type(8)));
typedef float  f32x4  __attribute__((ext_vector_type(4)));

__device__ inline ushort f2bf(float f) {
  union { float f; uint32_t u; } v; v.f = f;
  uint32_t r = v.u + 0x7FFF + ((v.u >> 16) & 1);   // RNE
  return (ushort)(r >> 16);
}
__device__ inline float bf2f(ushort u) {
  union { uint32_t u; float f; } v; v.u = ((uint32_t)u) << 16;
  return v.f;
}

__device__ inline void gload16(const void* g, void* l) {
  __builtin_amdgcn_global_load_lds(
      (const __attribute__((address_space(1))) void*)g,
      (__attribute__((address_space(3))) void*)l, 16, 0, 0);
}

// ---------------- prep: lambda (complex), exp(gamma) ----------------
__global__ __launch_bounds__(256) void prep_kernel(
    const float* __restrict__ nu_log, const float* __restrict__ theta_log,
    const float* __restrict__ gamma_log,
    float* __restrict__ lam_re, float* __restrict__ lam_im, float* __restrict__ eg) {
  int h = blockIdx.x * 256 + threadIdx.x;
  if (h < HID) {
    float mag = expf(-expf(nu_log[h]));
    float th  = expf(theta_log[h]);
    lam_re[h] = mag * cosf(th);
    lam_im[h] = mag * sinf(th);
    eg[h]     = expf(gamma_log[h]);
  }
}

// ---------------- fp32 -> bf16, vectorized x4 ----------------
__global__ __launch_bounds__(256) void convX(
    const float* __restrict__ src, ushort* __restrict__ dst) {
  size_t i = ((size_t)blockIdx.x * 256 + threadIdx.x) * 4;
  float4 v = *(const float4*)(src + i);
  ushort4 o;
  o.x = f2bf(v.x); o.y = f2bf(v.y); o.z = f2bf(v.z); o.w = f2bf(v.w);
  *(ushort4*)(dst + i) = o;
}

// ---------------- all weight prep in one kernel (z selects job) ----------------
__global__ __launch_bounds__(256) void weight_prep(
    const float* __restrict__ Bre, const float* __restrict__ Bim,
    const float* __restrict__ Cre, const float* __restrict__ Cim,
    const float* __restrict__ D,   const float* __restrict__ eg,
    ushort* __restrict__ BreT, ushort* __restrict__ BimT,
    ushort* __restrict__ CreB, ushort* __restrict__ CimB,
    ushort* __restrict__ DT) {
  __shared__ float tile[32][33];
  int z = blockIdx.z;
  if (z == 2 || z == 3) {
    const float* src = (z == 2) ? Cre : Cim;
    ushort* dst = (z == 2) ? CreB : CimB;
    float s = (z == 2) ? 1.0f : -1.0f;
    size_t base = ((size_t)blockIdx.y * 32 + (threadIdx.x >> 3)) * 1024 +
                  blockIdx.x * 32 + (threadIdx.x & 7) * 4;
    float4 v = *(const float4*)(src + base);
    ushort4 o;
    o.x = f2bf(v.x * s); o.y = f2bf(v.y * s);
    o.z = f2bf(v.z * s); o.w = f2bf(v.w * s);
    *(ushort4*)(dst + base) = o;
    return;
  }
  const float* src = (z == 0) ? Bre : (z == 1) ? Bim : D;
  ushort* dst = (z == 0) ? BreT : (z == 1) ? BimT : DT;
  bool scaled = (z < 2);
  int bx = blockIdx.x * 32;   // n-block
  int by = blockIdx.y * 32;   // k-block
  int tx = threadIdx.x & 31, ty = threadIdx.x >> 5;
#pragma unroll
  for (int r = 0; r < 32; r += 8)
    tile[ty + r][tx] = src[(size_t)(by + ty + r) * 1024 + bx + tx];
  __syncthreads();
  float sc = scaled ? eg[by + tx] : 1.0f;
#pragma unroll
  for (int r = 0; r < 32; r += 8)
    dst[(size_t)(bx + ty + r) * 1024 + by + tx] = f2bf(tile[tx][ty + r] * sc);
}

// ============ 256x256 SINGLE-BARRIER 8-phase MFMA GEMM ============
// 512 threads = 8 waves (2 M x 4 N). Per-wave output 128x64.
// Phase p = { ds_read(p) issue; stage issue; [VM4]; FEN; BAR; FEN; MFMA(p) }.
// Raw s_barrier is IntrNoMem -> NOT a compiler memory fence; the FEN()
// (empty asm, memory clobber, zero instructions) pins every LDS read and
// global_load_lds inside its phase window so the hazard proof below holds.
// Hazard proof: reads R={P1:A0B0,P2:B0,P3:A0,P5:A1B1,P6:B1,P7:A1};
// stages S={P1:A1, P4:B0, P5:A0, P8:B1}. S(p) avoids R(p) and R(p-1)
// (reads of window p may still be in flight during window p+1, so the
// constraint is S(p+1) disjoint R(p) -- holds for all p).
// Staged-tile completion: VM4@P4 + BAR completes {prevP8(B1), P1(A1)} before
// P5 reads them; VM4@P8 + BAR completes {P4(B0), P5(A0)} before next P1.
// Last iteration: VM0@P4 (nothing else in flight afterward).
// No explicit lgkmcnt: fragment loads are C++ loads; the compiler emits
// progressive lgkmcnt from register dataflow (first MFMA starts early).

#define BAR()   __builtin_amdgcn_s_barrier()
#define FEN()   asm volatile("" ::: "memory")
#define VM4()   asm volatile("s_waitcnt vmcnt(4)" ::: "memory")
#define VM0()   asm volatile("s_waitcnt vmcnt(0)" ::: "memory")
#define PBAR()  do { FEN(); BAR(); FEN(); } while (0)

#define STAGE_HALF(G, LDA, R0, K0, LT, HALF)                         \
  do {                                                               \
    _Pragma("unroll")                                                \
    for (int is_ = 0; is_ < 2; ++is_) {                              \
      int seg_ = w * 2 + is_;                                        \
      int gr_ = (R0) + (HALF) * 128 + seg_ * 8 + (l >> 3);           \
      int gc_ = (K0) + (((l & 7) ^ (l >> 3)) << 3);                  \
      gload16((G) + (size_t)gr_ * (LDA) + gc_,                       \
              (LT) + (HALF) * 8192 + seg_ * 512);                    \
    }                                                                \
  } while (0)

#define DS_A(QM, BUF)                                                \
  do {                                                               \
    _Pragma("unroll")                                                \
    for (int m_ = 0; m_ < 4; ++m_) {                                 \
      int r_ = (wr * 128 + ((QM) * 4 + m_) * 16 + lo) * 64;          \
      a[m_][0] = *(const bf16x8*)((BUF) + r_ + c0us);                \
      a[m_][1] = *(const bf16x8*)((BUF) + r_ + c1us);                \
    }                                                                \
  } while (0)

#define DS_B(QN, BUF, REG)                                           \
  do {                                                               \
    _Pragma("unroll")                                                \
    for (int n_ = 0; n_ < 2; ++n_) {                                 \
      int r_ = (wc * 64 + ((QN) * 2 + n_) * 16 + lo) * 64;           \
      REG[n_][0] = *(const bf16x8*)((BUF) + r_ + c0us);              \
      REG[n_][1] = *(const bf16x8*)((BUF) + r_ + c1us);              \
    }                                                                \
  } while (0)

#define MFMA_Q(QM, QN, REG)                                          \
  do {                                                               \
    __builtin_amdgcn_s_setprio(1);                                   \
    _Pragma("unroll")                                                \
    for (int m_ = 0; m_ < 4; ++m_)                                   \
      _Pragma("unroll")                                              \
      for (int n_ = 0; n_ < 2; ++n_) {                               \
        f32x4* ac_ = &acc[(QM) * 4 + m_][(QN) * 2 + n_];             \
        *ac_ = __builtin_amdgcn_mfma_f32_16x16x32_bf16(              \
            a[m_][0], REG[n_][0], *ac_, 0, 0, 0);                    \
        *ac_ = __builtin_amdgcn_mfma_f32_16x16x32_bf16(              \
            a[m_][1], REG[n_][1], *ac_, 0, 0, 0);                    \
      }                                                              \
    __builtin_amdgcn_s_setprio(0);                                   \
  } while (0)

// NSEG chained K=1024 segments as one continuous tile stream (no drains).
template<int NSEG>
__device__ __forceinline__ void gemm256_1bar(
    const ushort* Ap0, int ld0, const ushort* Bp0,
    const ushort* Ap1, int ld1, const ushort* Bp1,
    const ushort* Ap2, int ld2, const ushort* Bp2,
    ushort* lds, int row0, int col0,
    int w, int l, int wr, int wc, int lo, int c0us, int c1us,
    f32x4 (&acc)[8][4]) {
  ushort* A0 = lds;
  ushort* A1 = lds + 16384;
  ushort* B0 = lds + 32768;
  ushort* B1 = lds + 49152;
  bf16x8 a[4][2], bq0[2][2], bq1[2][2];
  const int NT = NSEG * 16;

  auto stageA = [&](int t, ushort* buf) {
    const ushort* A; int lda;
    if constexpr (NSEG == 1) { A = Ap0; lda = ld0; }
    else {
      if (t < 16)      { A = Ap0; lda = ld0; }
      else if (t < 32) { A = Ap1; lda = ld1; }
      else             { A = Ap2; lda = ld2; }
    }
    const int kk = (t & 15) * 64;
    STAGE_HALF(A, lda, row0, kk, buf, 0);
    STAGE_HALF(A, lda, row0, kk, buf, 1);
  };
  auto stageB = [&](int t, ushort* buf) {
    const ushort* B;
    if constexpr (NSEG == 1) { B = Bp0; }
    else {
      if (t < 16)      B = Bp0;
      else if (t < 32) B = Bp1;
      else             B = Bp2;
    }
    const int kk = (t & 15) * 64;
    STAGE_HALF(B, 1024, col0, kk, buf, 0);
    STAGE_HALF(B, 1024, col0, kk, buf, 1);
  };

  // prologue: t0.A->A0, t0.B->B0, t1.B->B1 (12 gloads); wait t0 complete.
  stageA(0, A0); stageB(0, B0); stageB(1, B1);
  VM4(); PBAR();

#pragma unroll 1
  for (int j = 0; j < NT / 2; ++j) {
    const int t1 = 2 * j + 1, t2 = 2 * j + 2, t3 = 2 * j + 3;
    const bool st = (t2 < NT);
    // P1: reads {A0.q0, B0.q0}; stage A1 <- t1.A
    DS_A(0, A0); DS_B(0, B0, bq0);
    stageA(t1, A1);
    PBAR(); MFMA_Q(0, 0, bq0);
    // P2: reads {B0.q1}
    DS_B(1, B0, bq1);
    PBAR(); MFMA_Q(0, 1, bq1);
    // P3: reads {A0.q1}
    DS_A(1, A0);
    PBAR(); MFMA_Q(1, 0, bq0);
    // P4: stage B0 <- t2.B; VM4 completes {prevP8(B1), P1(A1)}
    if (st) { stageB(t2, B0); VM4(); } else { VM0(); }
    PBAR(); MFMA_Q(1, 1, bq1);
    // P5: reads {A1.q0, B1.q0}; stage A0 <- t2.A
    DS_A(0, A1); DS_B(0, B1, bq0);
    if (st) stageA(t2, A0);
    PBAR(); MFMA_Q(0, 0, bq0);
    // P6: reads {B1.q1}
    DS_B(1, B1, bq1);
    PBAR(); MFMA_Q(0, 1, bq1);
    // P7: reads {A1.q1}
    DS_A(1, A1);
    PBAR(); MFMA_Q(1, 0, bq0);
    // P8: stage B1 <- t3.B; VM4 completes {P4(B0), P5(A0)}
    if (st) { stageB(t3, B1); VM4(); }
    PBAR(); MFMA_Q(1, 1, bq1);
  }
}

// ---------------- Bu GEMM: X @ [BreT;BimT]^T -> bf16 T x 2048 ----------------
__global__ __launch_bounds__(512, 2) void gemm_bu(
    const ushort* __restrict__ A, const ushort* __restrict__ B,
    ushort* __restrict__ O) {
  __shared__ __align__(16) ushort lds[65536];
  const int tid = threadIdx.x;
  const int w = tid >> 6, l = tid & 63;
  const int wr = w >> 2, wc = w & 3;
  const int lo = l & 15, q = l >> 4;
  const int xorv = (lo & 7) << 4;
  const int c0us = ((q * 16) ^ xorv) >> 1;
  const int c1us = ((64 + q * 16) ^ xorv) >> 1;
  // XCD-grouped mapping: XCD x owns row-panels [8x,8x+8) x all 8 col-panels.
  const int id = blockIdx.x;
  const int xcd = id & 7, slot = id >> 3;
  const int row0 = (xcd * 8 + (slot >> 3)) * 256;
  const int col0 = (slot & 7) * 256;
  f32x4 acc[8][4];
#pragma unroll
  for (int m = 0; m < 8; ++m)
#pragma unroll
    for (int n = 0; n < 4; ++n) acc[m][n] = (f32x4){0.f, 0.f, 0.f, 0.f};
  gemm256_1bar<1>(A, 1024, B, A, 1024, B, A, 1024, B,
                  lds, row0, col0, w, l, wr, wc, lo, c0us, c1us, acc);
  const int rowb = row0 + wr * 128, colb = col0 + wc * 64;
#pragma unroll
  for (int m = 0; m < 8; ++m)
#pragma unroll
    for (int n = 0; n < 4; ++n) {
      int col = colb + n * 16 + lo;
#pragma unroll
      for (int r = 0; r < 4; ++r)
        O[(size_t)(rowb + m * 16 + q * 4 + r) * 2048 + col] = f2bf(acc[m][n][r]);
    }
}

// ---------------- out = Hre@Cre^T + Him@(-Cim)^T + X@D^T ----------------
__global__ __launch_bounds__(512, 2) void gemm3(
    const ushort* __restrict__ Hall,
    const ushort* __restrict__ CreB, const ushort* __restrict__ CimB,
    const ushort* __restrict__ X,    const ushort* __restrict__ DT,
    float* __restrict__ O) {
  __shared__ __align__(16) ushort lds[65536];
  const int tid = threadIdx.x;
  const int w = tid >> 6, l = tid & 63;
  const int wr = w >> 2, wc = w & 3;
  const int lo = l & 15, q = l >> 4;
  const int xorv = (lo & 7) << 4;
  const int c0us = ((q * 16) ^ xorv) >> 1;
  const int c1us = ((64 + q * 16) ^ xorv) >> 1;
  // XCD-grouped mapping: XCD x owns row-panels [8x,8x+8) x all 4 col-panels.
  const int id = blockIdx.x;
  const int xcd = id & 7, slot = id >> 3;
  const int row0 = (xcd * 8 + (slot >> 2)) * 256;
  const int col0 = (slot & 3) * 256;
  f32x4 acc[8][4];
#pragma unroll
  for (int m = 0; m < 8; ++m)
#pragma unroll
    for (int n = 0; n < 4; ++n) acc[m][n] = (f32x4){0.f, 0.f, 0.f, 0.f};
  gemm256_1bar<3>(Hall, 2048, CreB,
                  Hall + 1024, 2048, CimB,
                  X, 1024, DT,
                  lds, row0, col0, w, l, wr, wc, lo, c0us, c1us, acc);
  const int rowb = row0 + wr * 128, colb = col0 + wc * 64;
#pragma unroll
  for (int m = 0; m < 8; ++m)
#pragma unroll
    for (int n = 0; n < 4; ++n) {
      int col = colb + n * 16 + lo;
#pragma unroll
      for (int r = 0; r < 4; ++r)
        O[(size_t)(rowb + m * 16 + q * 4 + r) * HID + col] = acc[m][n][r];
    }
}

// ---------------- scan pass A: chunk sums only (Bu: T x 2048 bf16) -------------
__global__ __launch_bounds__(256) void scan_sums(
    const ushort* __restrict__ Bu,
    const float* __restrict__ lam_re, const float* __restrict__ lam_im,
    float* __restrict__ Sre, float* __restrict__ Sim) {
  int h0 = (blockIdx.y * 256 + threadIdx.x) * 2;
  int c = blockIdx.x;
  float lr0 = lam_re[h0], li0 = lam_im[h0];
  float lr1 = lam_re[h0 + 1], li1 = lam_im[h0 + 1];
  float hr0 = 0.f, hi0 = 0.f, hr1 = 0.f, hi1 = 0.f;
  const uint* P = (const uint*)Bu;
  size_t baseR = (size_t)c * CHUNK * 1024 + (h0 >> 1);          // uint idx, row stride 1024
  size_t baseI = baseR + 512;
#pragma unroll 8
  for (int t = 0; t < CHUNK; ++t) {
    uint re = P[baseR + (size_t)t * 1024];
    uint im = P[baseI + (size_t)t * 1024];
    float br0 = bf2f((ushort)re), br1 = bf2f((ushort)(re >> 16));
    float bi0 = bf2f((ushort)im), bi1 = bf2f((ushort)(im >> 16));
    float nr0 = fmaf(lr0, hr0, fmaf(-li0, hi0, br0));
    float ni0 = fmaf(lr0, hi0, fmaf(li0, hr0, bi0));
    float nr1 = fmaf(lr1, hr1, fmaf(-li1, hi1, br1));
    float ni1 = fmaf(lr1, hi1, fmaf(li1, hr1, bi1));
    hr0 = nr0; hi0 = ni0; hr1 = nr1; hi1 = ni1;
  }
  Sre[(size_t)c * HID + h0] = hr0;  Sre[(size_t)c * HID + h0 + 1] = hr1;
  Sim[(size_t)c * HID + h0] = hi0;  Sim[(size_t)c * HID + h0 + 1] = hi1;
}

// ---------------- scan pass 2: serial carry scan over chunks ----------------
__global__ __launch_bounds__(256) void scan_carry(
    const float* __restrict__ Sre, const float* __restrict__ Sim,
    const float* __restrict__ lam_re, const float* __restrict__ lam_im,
    float* __restrict__ Pre, float* __restrict__ Pim) {
  int h = blockIdx.x * 256 + threadIdx.x;
  float lr = lam_re[h], li = lam_im[h];
  float pr = lr, pi = li;       // lambda^64 via 6 squarings
#pragma unroll
  for (int s = 0; s < 6; ++s) {
    float nr = pr * pr - pi * pi;
    float ni = 2.f * pr * pi;
    pr = nr; pi = ni;
  }
  float cr = 0.f, ci = 0.f;
  for (int c = 0; c < NCHUNK; ++c) {
    Pre[(size_t)c * HID + h] = cr;
    Pim[(size_t)c * HID + h] = ci;
    float sr = Sre[(size_t)c * HID + h];
    float si = Sim[(size_t)c * HID + h];
    float nr = fmaf(pr, cr, fmaf(-pi, ci, sr));
    float ni = fmaf(pr, ci, fmaf(pi, cr, si));
    cr = nr; ci = ni;
  }
}

// ---------------- scan pass B: replay with carry init, emit bf16 Hall ----------
__global__ __launch_bounds__(256) void scan_emit(
    const ushort* __restrict__ Bu,
    const float* __restrict__ lam_re, const float* __restrict__ lam_im,
    const float* __restrict__ Pre, const float* __restrict__ Pim,
    ushort* __restrict__ Hall) {
  int h0 = (blockIdx.y * 256 + threadIdx.x) * 2;
  int c = blockIdx.x;
  float lr0 = lam_re[h0], li0 = lam_im[h0];
  float lr1 = lam_re[h0 + 1], li1 = lam_im[h0 + 1];
  float hr0 = Pre[(size_t)c * HID + h0], hi0 = Pim[(size_t)c * HID + h0];
  float hr1 = Pre[(size_t)c * HID + h0 + 1], hi1 = Pim[(size_t)c * HID + h0 + 1];
  const uint* P = (const uint*)Bu;
  uint* Q = (uint*)Hall;
  size_t baseR = (size_t)c * CHUNK * 1024 + (h0 >> 1);
  size_t baseI = baseR + 512;
#pragma unroll 8
  for (int t = 0; t < CHUNK; ++t) {
    uint re = P[baseR + (size_t)t * 1024];
    uint im = P[baseI + (size_t)t * 1024];
    float br0 = bf2f((ushort)re), br1 = bf2f((ushort)(re >> 16));
    float bi0 = bf2f((ushort)im), bi1 = bf2f((ushort)(im >> 16));
    float nr0 = fmaf(lr0, hr0, fmaf(-li0, hi0, br0));
    float ni0 = fmaf(lr0, hi0, fmaf(li0, hr0, bi0));
    float nr1 = fmaf(lr1, hr1, fmaf(-li1, hi1, br1));
    float ni1 = fmaf(lr1, hi1, fmaf(li1, hr1, bi1));
    hr0 = nr0; hi0 = ni0; hr1 = nr1; hi1 = ni1;
    Q[baseR + (size_t)t * 1024] = (uint)f2bf(hr0) | ((uint)f2bf(hr1) << 16);
    Q[baseI + (size_t)t * 1024] = (uint)f2bf(hi0) | ((uint)f2bf(hi1) << 16);
  }
}

extern "C" void kernel_launch(void* const* d_in, const int* in_sizes, int n_in,
                              void* d_out, int out_size, void* d_ws, size_t ws_size,
                              hipStream_t stream) {
  const float* inputs    = (const float*)d_in[0];
  const float* nu_log    = (const float*)d_in[1];
  const float* theta_log = (const float*)d_in[2];
  const float* gamma_log = (const float*)d_in[3];
  const float* B_re      = (const float*)d_in[4];
  const float* B_im      = (const float*)d_in[5];
  const float* C_re      = (const float*)d_in[6];
  const float* C_im      = (const float*)d_in[7];
  const float* D         = (const float*)d_in[8];
  float* out = (float*)d_out;

  char* ws = (char*)d_ws;
  constexpr size_t TH = (size_t)T_LEN * HID;       // 16.8M
  constexpr size_t W  = (size_t)1024 * 1024;
  constexpr size_t CH = (size_t)NCHUNK * HID;

  ushort* Xbf  = (ushort*)(ws);                    // TH*2
  ushort* Bu   = (ushort*)(ws + TH * 2);           // TH*2*2 (T x 2048)
  ushort* Hall = (ushort*)(ws + TH * 6);           // TH*2*2 (T x 2048)
  char*   p    = ws + TH * 10;
  ushort* Ball = (ushort*)(p);             p += 2 * W * 2;   // [BreT; BimT]
  ushort* CreB = (ushort*)(p);             p += W * 2;
  ushort* CimB = (ushort*)(p);             p += W * 2;
  ushort* DT   = (ushort*)(p);             p += W * 2;
  float*  Sre  = (float*)(p);              p += CH * 4;
  float*  Sim  = (float*)(p);              p += CH * 4;
  float*  Pre  = (float*)(p);              p += CH * 4;
  float*  Pim  = (float*)(p);              p += CH * 4;
  float*  lamR = (float*)(p);              p += 4096;
  float*  lamI = (float*)(p);              p += 4096;
  float*  eg   = (float*)(p);              p += 4096;
  ushort* BreT = Ball;
  ushort* BimT = Ball + W;

  prep_kernel<<<dim3(HID / 256), 256, 0, stream>>>(nu_log, theta_log, gamma_log,
                                                   lamR, lamI, eg);
  convX<<<dim3((unsigned)(TH / 4 / 256)), 256, 0, stream>>>(inputs, Xbf);
  weight_prep<<<dim3(32, 32, 5), 256, 0, stream>>>(B_re, B_im, C_re, C_im, D, eg,
                                                   BreT, BimT, CreB, CimB, DT);

  gemm_bu<<<dim3(512), 512, 0, stream>>>(Xbf, Ball, Bu);

  scan_sums<<<dim3(NCHUNK, HID / 512), 256, 0, stream>>>(Bu, lamR, lamI, Sre, Sim);
  scan_carry<<<dim3(HID / 256), 256, 0, stream>>>(Sre, Sim, lamR, lamI, Pre, Pim);
  scan_emit<<<dim3(NCHUNK, HID / 512), 256, 0, stream>>>(Bu, lamR, lamI, Pre, Pim,
                                                         Hall);

  gemm3<<<dim3(256), 512, 0, stream>>>(Hall, CreB, CimB, Xbf, DT, out);
}